// Round 7
// baseline (1463.660 us; speedup 1.0000x reference)
//
#include <hip/hip_runtime.h>
#include <cmath>

#define TBUF 1024
#define RCH  256

typedef __bf16 bf16x8 __attribute__((ext_vector_type(8)));
typedef float  f32x4  __attribute__((ext_vector_type(4)));

__device__ inline unsigned short f2bf(float f) {
  unsigned u = __builtin_bit_cast(unsigned, f);
  u += 0x7FFFu + ((u >> 16) & 1u);
  return (unsigned short)(u >> 16);
}

__device__ __forceinline__ void gl2lds(const unsigned short* g, unsigned short* l) {
  __builtin_amdgcn_global_load_lds(
      (const __attribute__((address_space(1))) unsigned int*)g,
      (__attribute__((address_space(3))) unsigned int*)l, 16, 0, 0);
}

// ---------------- weight transforms ----------------
// Wb[i][o'][kappa] bf16.  o'<256 -> filter o, o'>=256 -> gate o-256.
// kappa<256 -> current tap (w[...,1]), kappa>=256 -> previous tap (w[...,0]).
__global__ __launch_bounds__(256) void transform_fgb(
    const float* __restrict__ wf, const float* __restrict__ wg, unsigned short* __restrict__ Wb)
{
  int idx = blockIdx.x * 256 + threadIdx.x;      // < 32*512*256
  int c  = idx & 255;
  int op = (idx >> 8) & 511;
  int i  = idx >> 17;
  int o  = op & 255;
  const float* src = (op < 256) ? wf : wg;
  const float2 v = *(const float2*)&src[(((size_t)i * 256 + o) * 256 + c) << 1];
  unsigned short* dst = Wb + ((size_t)i * 512 + op) * 512;
  dst[c]       = f2bf(v.y);   // current tap (k=1)
  dst[256 + c] = f2bf(v.x);   // previous tap (k=0)
}

// Wrb[i][o][c] bf16 (w_res already [o][c])
__global__ __launch_bounds__(256) void transform_resb(
    const float* __restrict__ wr, unsigned short* __restrict__ Wrb)
{
  int idx = blockIdx.x * 256 + threadIdx.x;    // < 32*256*256/4
  float4 v = ((const float4*)wr)[idx];
  uint2 o;
  o.x = (unsigned)f2bf(v.x) | ((unsigned)f2bf(v.y) << 16);
  o.y = (unsigned)f2bf(v.z) | ((unsigned)f2bf(v.w) << 16);
  ((uint2*)Wrb)[idx] = o;
}

// wskT[i][c][s] = w_skip[i][s][c]  (fp32, for head)
__global__ __launch_bounds__(256) void transform_skip(
    const float* __restrict__ wsk, float* __restrict__ wskT)
{
  int idx = blockIdx.x * 256 + threadIdx.x;    // < 32*256*128
  int s = idx & 127;
  int c = (idx >> 7) & 255;
  int i = idx >> 15;
  wskT[idx] = wsk[(i * 128 + s) * 256 + c];
}

// w2[k*32+f][r] = w_in[r][f][k]
__global__ __launch_bounds__(256) void transform_w2(
    const float* __restrict__ w_in, float* __restrict__ w2)
{
  int idx = blockIdx.x * 256 + threadIdx.x;    // < 64*256
  int r = idx & 255;
  int fk = idx >> 8;
  int f = fk & 31, k = fk >> 5;
  w2[idx] = w_in[r * 64 + f * 2 + k];
}

// ---------------- input conv (F=32 -> R=256, K=2, d=1) ----------------
// grid (64 chunks, 16 batch); 16 tt rows per block; thread = output channel r.
__global__ __launch_bounds__(256) void in_conv(
    const float* __restrict__ X, const float* __restrict__ w2,
    const float* __restrict__ b_in, float* __restrict__ xb,
    unsigned short* __restrict__ xbb)
{
  const int chunk = blockIdx.x;
  const int b     = blockIdx.y;
  const int r     = threadIdx.x;
  __shared__ float Xs[17][32];
  const int tt0 = chunk << 4;
  const int t0  = tt0 + 1024;
  for (int idx = r; idx < 17 * 32; idx += 256) {
    int row = idx >> 5, f = idx & 31;
    Xs[row][f] = X[((size_t)b * 2048 + (t0 - 1 + row)) * 32 + f];
  }
  __syncthreads();
  float w0[32], w1[32];
  #pragma unroll
  for (int f = 0; f < 32; ++f) {
    w0[f] = w2[f * 256 + r];          // tap k=0 -> x[t-1]
    w1[f] = w2[(32 + f) * 256 + r];   // tap k=1 -> x[t]
  }
  const float bias = b_in[r];
  float4 prev[8], cur[8];
  #pragma unroll
  for (int q = 0; q < 8; ++q) prev[q] = *(const float4*)&Xs[0][q * 4];
  #pragma unroll
  for (int j = 0; j < 16; ++j) {
    #pragma unroll
    for (int q = 0; q < 8; ++q) cur[q] = *(const float4*)&Xs[j + 1][q * 4];
    float s0 = bias, s1 = 0.f, s2 = 0.f, s3 = 0.f;
    #pragma unroll
    for (int q = 0; q < 8; q += 4) {
      s0 = fmaf(w0[(q+0)*4+0], prev[q+0].x, s0); s0 = fmaf(w1[(q+0)*4+0], cur[q+0].x, s0);
      s1 = fmaf(w0[(q+0)*4+1], prev[q+0].y, s1); s1 = fmaf(w1[(q+0)*4+1], cur[q+0].y, s1);
      s2 = fmaf(w0[(q+0)*4+2], prev[q+0].z, s2); s2 = fmaf(w1[(q+0)*4+2], cur[q+0].z, s2);
      s3 = fmaf(w0[(q+0)*4+3], prev[q+0].w, s3); s3 = fmaf(w1[(q+0)*4+3], cur[q+0].w, s3);
      s0 = fmaf(w0[(q+1)*4+0], prev[q+1].x, s0); s0 = fmaf(w1[(q+1)*4+0], cur[q+1].x, s0);
      s1 = fmaf(w0[(q+1)*4+1], prev[q+1].y, s1); s1 = fmaf(w1[(q+1)*4+1], cur[q+1].y, s1);
      s2 = fmaf(w0[(q+1)*4+2], prev[q+1].z, s2); s2 = fmaf(w1[(q+1)*4+2], cur[q+1].z, s2);
      s3 = fmaf(w0[(q+1)*4+3], prev[q+1].w, s3); s3 = fmaf(w1[(q+1)*4+3], cur[q+1].w, s3);
      s0 = fmaf(w0[(q+2)*4+0], prev[q+2].x, s0); s0 = fmaf(w1[(q+2)*4+0], cur[q+2].x, s0);
      s1 = fmaf(w0[(q+2)*4+1], prev[q+2].y, s1); s1 = fmaf(w1[(q+2)*4+1], cur[q+2].y, s1);
      s2 = fmaf(w0[(q+2)*4+2], prev[q+2].z, s2); s2 = fmaf(w1[(q+2)*4+2], cur[q+2].z, s2);
      s3 = fmaf(w0[(q+2)*4+3], prev[q+2].w, s3); s3 = fmaf(w1[(q+2)*4+3], cur[q+2].w, s3);
      s0 = fmaf(w0[(q+3)*4+0], prev[q+3].x, s0); s0 = fmaf(w1[(q+3)*4+0], cur[q+3].x, s0);
      s1 = fmaf(w0[(q+3)*4+1], prev[q+3].y, s1); s1 = fmaf(w1[(q+3)*4+1], cur[q+3].y, s1);
      s2 = fmaf(w0[(q+3)*4+2], prev[q+3].z, s2); s2 = fmaf(w1[(q+3)*4+2], cur[q+3].z, s2);
      s3 = fmaf(w0[(q+3)*4+3], prev[q+3].w, s3); s3 = fmaf(w1[(q+3)*4+3], cur[q+3].w, s3);
    }
    float a = (s0 + s1) + (s2 + s3);
    int tt = tt0 + j;
    size_t off = ((size_t)b * TBUF + tt) * RCH + r;
    if (tt < 3) { xb[off] = 0.f; xbb[off] = 0; }
    else        { xb[off] = a;   xbb[off] = f2bf(a); }
    #pragma unroll
    for (int q = 0; q < 8; ++q) prev[q] = cur[q];
  }
}

// ---------------- conv GEMM (m97 structure): 128M x 128N(64f+64g) x K512 ----------------
// 256 thr = 4 waves (2x2), wave tile 64x64. Double-buffered LDS A+B, gload_lds w16,
// one barrier per K-step. grid (ceil(W/128), 4, 16).
__global__ __launch_bounds__(256, 3) void conv_mfma2(
    const unsigned short* __restrict__ xbb_r, unsigned short* __restrict__ zbb,
    const unsigned short* __restrict__ WbL, const float* __restrict__ bF,
    const float* __restrict__ bG, int dd, int t_lo)
{
  __shared__ __align__(16) unsigned short As[2][128 * 32];
  __shared__ __align__(16) unsigned short Bs[2][128 * 32];
  const int tid = threadIdx.x;
  const int w = tid >> 6, lane = tid & 63;
  const int wm = w >> 1, wn = w & 1;
  const int l15 = lane & 15, lk8 = (lane >> 4) << 3;
  const int tt0 = t_lo + (int)blockIdx.x * 128;
  const int ob  = (int)blockIdx.y << 6;     // f-col base (0,64,128,192)
  const int b   = blockIdx.z;
  const unsigned short* xB = xbb_r + ((size_t)b << 18);
  const int ca0 = (w << 7) + lane;          // staging chunk id (q=0)

  f32x4 acc[4][4] = {};

  auto stage = [&](int buf, int kc) {
    #pragma unroll
    for (int q = 0; q < 2; ++q) {
      int c = ca0 + (q << 6);
      int r = c >> 2, c4 = c & 3;
      int tt = tt0 + r - ((kc & 8) ? dd : 0);
      tt = min(max(tt, 0), 1023);
      gl2lds(xB + (tt << 8) + ((kc & 7) << 5) + (c4 << 3), &As[buf][c << 3]);
      int op = (r < 64) ? (ob + r) : (192 + ob + r);   // g rows at 256+ob+(r-64)
      gl2lds(WbL + ((size_t)op << 9) + (kc << 5) + (c4 << 3), &Bs[buf][c << 3]);
    }
  };

  stage(0, 0);
  __syncthreads();
  int cur = 0;
  #pragma unroll 2
  for (int kc = 0; kc < 16; ++kc) {
    if (kc + 1 < 16) stage(cur ^ 1, kc + 1);
    bf16x8 a[4], bb[4];
    #pragma unroll
    for (int mf = 0; mf < 4; ++mf)
      a[mf] = *(const bf16x8*)&As[cur][((wm << 6) + (mf << 4) + l15) * 32 + lk8];
    #pragma unroll
    for (int nf = 0; nf < 4; ++nf) {
      int rowB = (wn << 5) + ((nf & 1) << 4) + ((nf & 2) << 5);  // f rows 0-63, g rows 64-127
      bb[nf] = *(const bf16x8*)&Bs[cur][(rowB + l15) * 32 + lk8];
    }
    #pragma unroll
    for (int mf = 0; mf < 4; ++mf)
      #pragma unroll
      for (int nf = 0; nf < 4; ++nf)
        acc[mf][nf] = __builtin_amdgcn_mfma_f32_16x16x32_bf16(a[mf], bb[nf], acc[mf][nf], 0, 0, 0);
    if (kc + 1 < 16) { __syncthreads(); cur ^= 1; }
  }

  // gate epilogue: z = tanh(f+bf)*sigmoid(g+bg) -> zbb
  unsigned short* zB = zbb + ((size_t)b << 18);
  const int rr0 = (lane >> 4) << 2;
  #pragma unroll
  for (int nf = 0; nf < 2; ++nf) {
    int o = ob + (wn << 5) + (nf << 4) + l15;
    float bfv = bF[o], bgv = bG[o];
    #pragma unroll
    for (int mf = 0; mf < 4; ++mf) {
      int ttb = tt0 + (wm << 6) + (mf << 4) + rr0;
      #pragma unroll
      for (int j = 0; j < 4; ++j) {
        int tt = ttb + j;
        if (tt > 1023) continue;
        float pf = acc[mf][nf][j] + bfv;
        float pg = acc[mf][nf + 2][j] + bgv;
        float e2 = __expf(2.f * pf);
        float th = 1.f - 2.f / (e2 + 1.f);
        float sg = 1.f / (1.f + __expf(-pg));
        zB[(tt << 8) + o] = f2bf(th * sg);
      }
    }
  }
}

// ---------------- res GEMM: 128M x 128N x K256 + residual epilogue ----------------
// grid (ceil(W/128), 2, 16)
__global__ __launch_bounds__(256, 3) void res_mfma2(
    const unsigned short* __restrict__ zbb, float* __restrict__ xb,
    unsigned short* __restrict__ xbb_w, const unsigned short* __restrict__ WrL,
    const float* __restrict__ bR, int t_lo, float* __restrict__ fxs_i)
{
  __shared__ __align__(16) unsigned short As[2][128 * 32];
  __shared__ __align__(16) unsigned short Bs[2][128 * 32];
  const int tid = threadIdx.x;
  const int w = tid >> 6, lane = tid & 63;
  const int wm = w >> 1, wn = w & 1;
  const int l15 = lane & 15, lk8 = (lane >> 4) << 3;
  const int tt0 = t_lo + (int)blockIdx.x * 128;
  const int ob2 = (int)blockIdx.y << 7;     // 0 or 128
  const int b   = blockIdx.z;
  const unsigned short* zB = zbb + ((size_t)b << 18);
  const int ca0 = (w << 7) + lane;

  f32x4 acc[4][4] = {};

  auto stage = [&](int buf, int kc) {
    #pragma unroll
    for (int q = 0; q < 2; ++q) {
      int c = ca0 + (q << 6);
      int r = c >> 2, c4 = c & 3;
      int tt = min(tt0 + r, 1023);
      gl2lds(zB + (tt << 8) + (kc << 5) + (c4 << 3), &As[buf][c << 3]);
      gl2lds(WrL + ((size_t)(ob2 + r) << 8) + (kc << 5) + (c4 << 3), &Bs[buf][c << 3]);
    }
  };

  stage(0, 0);
  __syncthreads();
  int cur = 0;
  #pragma unroll 2
  for (int kc = 0; kc < 8; ++kc) {
    if (kc + 1 < 8) stage(cur ^ 1, kc + 1);
    bf16x8 a[4], bb[4];
    #pragma unroll
    for (int mf = 0; mf < 4; ++mf)
      a[mf] = *(const bf16x8*)&As[cur][((wm << 6) + (mf << 4) + l15) * 32 + lk8];
    #pragma unroll
    for (int nf = 0; nf < 4; ++nf)
      bb[nf] = *(const bf16x8*)&Bs[cur][((wn << 6) + (nf << 4) + l15) * 32 + lk8];
    #pragma unroll
    for (int mf = 0; mf < 4; ++mf)
      #pragma unroll
      for (int nf = 0; nf < 4; ++nf)
        acc[mf][nf] = __builtin_amdgcn_mfma_f32_16x16x32_bf16(a[mf], bb[nf], acc[mf][nf], 0, 0, 0);
    if (kc + 1 < 8) { __syncthreads(); cur ^= 1; }
  }

  // residual epilogue: fx = acc + bR; x += fx (fp32 master); bf16 mirror; fx snapshot
  float* xBf = xb + ((size_t)b << 18);
  unsigned short* xBb = xbb_w + ((size_t)b << 18);
  const int rr0 = (lane >> 4) << 2;
  #pragma unroll
  for (int nf = 0; nf < 4; ++nf) {
    int o = ob2 + (wn << 6) + (nf << 4) + l15;
    float brv = bR[o];
    #pragma unroll
    for (int mf = 0; mf < 4; ++mf) {
      int ttb = tt0 + (wm << 6) + (mf << 4) + rr0;
      #pragma unroll
      for (int j = 0; j < 4; ++j) {
        int tt = ttb + j;
        if (tt > 1023) continue;
        size_t off = ((size_t)tt << 8) + o;
        float fx = acc[mf][nf][j] + brv;
        float xn = xBf[off] + fx;
        xBf[off] = xn;
        xBb[off] = f2bf(xn);
        if (tt == 1023) fxs_i[(size_t)b * 256 + o] = fx;
      }
    }
  }
}

// ---------------- head ----------------
__global__ __launch_bounds__(128) void skip_partial(
    const float* __restrict__ fxs, const float* __restrict__ wskT,
    const float* __restrict__ b_skip, float* __restrict__ part)
{
  int i = blockIdx.x, b = blockIdx.y, s = threadIdx.x;
  __shared__ float fxsh[256];
  fxsh[s]       = fxs[((size_t)i * 16 + b) * 256 + s];
  fxsh[s + 128] = fxs[((size_t)i * 16 + b) * 256 + s + 128];
  __syncthreads();
  float a = b_skip[i * 128 + s];
  const float* wp = wskT + (size_t)i * 256 * 128 + s;
  #pragma unroll 4
  for (int c = 0; c < 256; c++)
    a = fmaf(wp[c * 128], fxsh[c], a);
  part[((size_t)i * 16 + b) * 128 + s] = a;
}

__global__ __launch_bounds__(128) void head2(
    const float* __restrict__ part, const float* __restrict__ w_o1,
    const float* __restrict__ b_o1, const float* __restrict__ w_o2,
    const float* __restrict__ b_o2, const float* __restrict__ w_lin,
    const float* __restrict__ b_lin, const float* __restrict__ Xex,
    float* __restrict__ out)
{
  int b = blockIdx.x, tid = threadIdx.x;
  __shared__ float sk[128];
  __shared__ float h1[64];
  __shared__ float hc[80];
  float a = 0.f;
  for (int i = 0; i < 32; i++) a += part[((size_t)i * 16 + b) * 128 + tid];
  sk[tid] = fmaxf(a, 0.f);
  __syncthreads();
  if (tid < 64) {
    float a1 = b_o1[tid];
    for (int s = 0; s < 128; s++) a1 = fmaf(w_o1[tid * 128 + s], sk[s], a1);
    h1[tid] = fmaxf(a1, 0.f);
  }
  __syncthreads();
  if (tid < 64) {
    float a2 = b_o2[tid];
    for (int j = 0; j < 64; j++) a2 = fmaf(w_o2[tid * 64 + j], h1[j], a2);
    hc[tid] = fmaxf(a2, 0.f);
  }
  if (tid >= 64 && tid < 80) hc[tid] = fmaxf(Xex[b * 16 + (tid - 64)], 0.f);
  __syncthreads();
  if (tid < 24) {
    float a3 = b_lin[tid];
    for (int j = 0; j < 80; j++) a3 = fmaf(w_lin[tid * 80 + j], hc[j], a3);
    out[b * 24 + tid] = a3;
  }
}

extern "C" void kernel_launch(void* const* d_in, const int* in_sizes, int n_in,
                              void* d_out, int out_size, void* d_ws, size_t ws_size,
                              hipStream_t stream)
{
  (void)in_sizes; (void)n_in; (void)out_size; (void)ws_size;
  const float* X     = (const float*)d_in[0];
  const float* Xex   = (const float*)d_in[1];
  const float* w_in  = (const float*)d_in[2];
  const float* b_in  = (const float*)d_in[3];
  const float* w_f   = (const float*)d_in[4];
  const float* b_f   = (const float*)d_in[5];
  const float* w_g   = (const float*)d_in[6];
  const float* b_g   = (const float*)d_in[7];
  const float* w_r   = (const float*)d_in[8];
  const float* b_r   = (const float*)d_in[9];
  const float* w_s   = (const float*)d_in[10];
  const float* b_s   = (const float*)d_in[11];
  const float* w_o1  = (const float*)d_in[12];
  const float* b_o1  = (const float*)d_in[13];
  const float* w_o2  = (const float*)d_in[14];
  const float* b_o2  = (const float*)d_in[15];
  const float* w_lin = (const float*)d_in[16];
  const float* b_lin = (const float*)d_in[17];

  float* ws   = (float*)d_ws;
  float* wskT = ws;                        // 1,048,576 f
  float* xb   = wskT + 1048576;            // 4,194,304 f
  float* fxs  = xb   + 4194304;            // 131,072 f
  float* part = fxs  + 131072;             // 65,536 f
  float* w2   = part + 65536;              // 16,384 f
  unsigned short* Wb   = (unsigned short*)(w2 + 16384);    // 8,388,608 us
  unsigned short* Wrb  = Wb   + 8388608;   // 2,097,152 us
  unsigned short* xbbA = Wrb  + 2097152;   // 4,194,304 us
  unsigned short* xbbB = xbbA + 4194304;   // 4,194,304 us
  unsigned short* zbb  = xbbB + 4194304;   // 4,194,304 us

  transform_fgb <<<16384, 256, 0, stream>>>(w_f, w_g, Wb);
  transform_resb<<<2048,  256, 0, stream>>>(w_r, Wrb);
  transform_skip<<<4096,  256, 0, stream>>>(w_s, wskT);
  transform_w2  <<<64,    256, 0, stream>>>(w_in, w2);
  in_conv<<<dim3(64, 16), 256, 0, stream>>>(X, w2, b_in, xb, xbbA);

  // suffix-window sizes: w[i] = w[i+1] + 2^(i%8), w[32] = 1
  static const int wI[33] = {1021,1020,1018,1014,1006,990,958,894,
                             766,765,763,759,751,735,703,639,
                             511,510,508,504,496,480,448,384,
                             256,255,253,249,241,225,193,129,1};
  for (int i = 0; i < 32; i++) {
    int dd    = 1 << (i & 7);
    int Wout  = wI[i + 1];
    int t_lo  = TBUF - Wout;
    int tiles = (Wout + 127) / 128;
    unsigned short* xin  = (i & 1) ? xbbB : xbbA;
    unsigned short* xout = (i & 1) ? xbbA : xbbB;
    conv_mfma2<<<dim3(tiles, 4, 16), 256, 0, stream>>>(
        xin, zbb, Wb + (size_t)i * 512 * 512, b_f + i * 256, b_g + i * 256, dd, t_lo);
    res_mfma2<<<dim3(tiles, 2, 16), 256, 0, stream>>>(
        zbb, xb, xout, Wrb + (size_t)i * 256 * 256, b_r + i * 256, t_lo,
        fxs + (size_t)i * 16 * 256);
  }
  skip_partial<<<dim3(32, 16), 128, 0, stream>>>(fxs, wskT, b_s, part);
  head2<<<16, 128, 0, stream>>>(part, w_o1, b_o1, w_o2, b_o2, w_lin, b_lin, Xex, (float*)d_out);
}

// Round 8
// 1379.202 us; speedup vs baseline: 1.0612x; 1.0612x over previous
//
#include <hip/hip_runtime.h>
#include <cmath>

#define TBUF 1024
#define RCH  256

typedef __bf16 bf16x8 __attribute__((ext_vector_type(8)));
typedef float  f32x4  __attribute__((ext_vector_type(4)));

__device__ inline unsigned short f2bf(float f) {
  unsigned u = __builtin_bit_cast(unsigned, f);
  u += 0x7FFFu + ((u >> 16) & 1u);
  return (unsigned short)(u >> 16);
}

// ---------------- weight transforms ----------------
// Wb[i][o'][kappa] bf16.  o'<256 -> filter o, o'>=256 -> gate o-256.
// kappa<256 -> current tap (w[...,1]), kappa>=256 -> previous tap (w[...,0]).
__global__ __launch_bounds__(256) void transform_fgb(
    const float* __restrict__ wf, const float* __restrict__ wg, unsigned short* __restrict__ Wb)
{
  int idx = blockIdx.x * 256 + threadIdx.x;      // < 32*512*256
  int c  = idx & 255;
  int op = (idx >> 8) & 511;
  int i  = idx >> 17;
  int o  = op & 255;
  const float* src = (op < 256) ? wf : wg;
  const float2 v = *(const float2*)&src[(((size_t)i * 256 + o) * 256 + c) << 1];
  unsigned short* dst = Wb + ((size_t)i * 512 + op) * 512;
  dst[c]       = f2bf(v.y);   // current tap (k=1)
  dst[256 + c] = f2bf(v.x);   // previous tap (k=0)
}

// Wrb[i][o][c] bf16 (w_res already [o][c])
__global__ __launch_bounds__(256) void transform_resb(
    const float* __restrict__ wr, unsigned short* __restrict__ Wrb)
{
  int idx = blockIdx.x * 256 + threadIdx.x;    // < 32*256*256/4
  float4 v = ((const float4*)wr)[idx];
  uint2 o;
  o.x = (unsigned)f2bf(v.x) | ((unsigned)f2bf(v.y) << 16);
  o.y = (unsigned)f2bf(v.z) | ((unsigned)f2bf(v.w) << 16);
  ((uint2*)Wrb)[idx] = o;
}

// wskT[i][c][s] = w_skip[i][s][c]  (fp32, for head)
__global__ __launch_bounds__(256) void transform_skip(
    const float* __restrict__ wsk, float* __restrict__ wskT)
{
  int idx = blockIdx.x * 256 + threadIdx.x;    // < 32*256*128
  int s = idx & 127;
  int c = (idx >> 7) & 255;
  int i = idx >> 15;
  wskT[idx] = wsk[(i * 128 + s) * 256 + c];
}

// w2[k*32+f][r] = w_in[r][f][k]
__global__ __launch_bounds__(256) void transform_w2(
    const float* __restrict__ w_in, float* __restrict__ w2)
{
  int idx = blockIdx.x * 256 + threadIdx.x;    // < 64*256
  int r = idx & 255;
  int fk = idx >> 8;
  int f = fk & 31, k = fk >> 5;
  w2[idx] = w_in[r * 64 + f * 2 + k];
}

// ---------------- input conv (F=32 -> R=256, K=2, d=1) ----------------
// 1D grid 1024 = 64 chunks x 16 batch, batch FASTEST (id&15) -> id%8 = batch%8 = XCD.
__global__ __launch_bounds__(256) void in_conv(
    const float* __restrict__ X, const float* __restrict__ w2,
    const float* __restrict__ b_in, float* __restrict__ xb,
    unsigned short* __restrict__ xbb)
{
  const int bid   = blockIdx.x;
  const int b     = bid & 15;
  const int chunk = bid >> 4;
  const int r     = threadIdx.x;
  __shared__ float Xs[17][32];
  const int tt0 = chunk << 4;
  const int t0  = tt0 + 1024;
  for (int idx = r; idx < 17 * 32; idx += 256) {
    int row = idx >> 5, f = idx & 31;
    Xs[row][f] = X[((size_t)b * 2048 + (t0 - 1 + row)) * 32 + f];
  }
  __syncthreads();
  float w0[32], w1[32];
  #pragma unroll
  for (int f = 0; f < 32; ++f) {
    w0[f] = w2[f * 256 + r];          // tap k=0 -> x[t-1]
    w1[f] = w2[(32 + f) * 256 + r];   // tap k=1 -> x[t]
  }
  const float bias = b_in[r];
  float4 prev[8], cur[8];
  #pragma unroll
  for (int q = 0; q < 8; ++q) prev[q] = *(const float4*)&Xs[0][q * 4];
  #pragma unroll
  for (int j = 0; j < 16; ++j) {
    #pragma unroll
    for (int q = 0; q < 8; ++q) cur[q] = *(const float4*)&Xs[j + 1][q * 4];
    float a = bias;
    #pragma unroll
    for (int q = 0; q < 8; ++q) {
      a = fmaf(w0[q*4+0], prev[q].x, a); a = fmaf(w1[q*4+0], cur[q].x, a);
      a = fmaf(w0[q*4+1], prev[q].y, a); a = fmaf(w1[q*4+1], cur[q].y, a);
      a = fmaf(w0[q*4+2], prev[q].z, a); a = fmaf(w1[q*4+2], cur[q].z, a);
      a = fmaf(w0[q*4+3], prev[q].w, a); a = fmaf(w1[q*4+3], cur[q].w, a);
    }
    int tt = tt0 + j;
    size_t off = ((size_t)b * TBUF + tt) * RCH + r;
    if (tt < 3) { xb[off] = 0.f; xbb[off] = 0; }
    else        { xb[off] = a;   xbb[off] = f2bf(a); }
    #pragma unroll
    for (int q = 0; q < 8; ++q) prev[q] = cur[q];
  }
}

// ---------------- fused layer: gated dilated conv + res 1x1 + residual ----------------
// 1D grid tiles*16, batch FASTEST: bid&15 = batch -> bid%8 = batch%8 = XCD.
// Each XCD owns 2 batches: its x slice (bf16 in/out mirrors + fp32 master ~4.6MB)
// stays L2-resident across ALL layers. 512 thr = 8 waves, M=64, full N.
// A-tile (64x512, both taps) in LDS, 1040B rows (odd stride = natural bank skew).
// launch_bounds(512,2) -> 256-VGPR budget, no spills (r3-verified).
__global__ __launch_bounds__(512, 2) void layer_fused(
    const unsigned short* __restrict__ xbb_r, float* __restrict__ xb,
    unsigned short* __restrict__ xbb_w,
    const unsigned short* __restrict__ Wb,   // [512][512] bf16
    const unsigned short* __restrict__ Wrb,  // [256][256] bf16
    const float* __restrict__ bF, const float* __restrict__ bG,
    const float* __restrict__ bR,
    int dd, int t_lo, float* __restrict__ fxs_i)
{
  __shared__ __align__(16) unsigned short As[64 * 520];   // 66,560 B; z aliases
  const int bid  = blockIdx.x;
  const int b    = bid & 15;
  const int tile = bid >> 4;
  const int tid  = threadIdx.x;
  const int w    = tid >> 6;
  const int lane = tid & 63;
  const int l15  = lane & 15;
  const int lk8  = (lane >> 4) << 3;          // k-elem offset {0,8,16,24}
  const int tt0  = t_lo + tile * 64;
  const unsigned short* xB = xbb_r + ((size_t)b << 18);

  // ---- stage full A tile: 64 rows x 512 k  (k<256: x[tt], k>=256: x[tt-d])
  #pragma unroll
  for (int it = 0; it < 8; ++it) {
    int flat = it * 512 + tid;
    int r = flat >> 6;                 // 0..63 (uniform per wave)
    int c = flat & 63;                 // 16B slot within row
    int tap = c >> 5;
    int tt = tt0 + r - tap * dd;
    tt = min(max(tt, 0), 1023);
    uint4 v = *(const uint4*)&xB[((size_t)tt << 8) + ((c & 31) << 3)];
    *(uint4*)((char*)As + r * 1040 + (c << 4)) = v;
  }
  __syncthreads();

  // ---- conv GEMM (no barriers): per wave 64(M) x {32 f + 32 g}
  f32x4 accf[4][2] = {};
  f32x4 accg[4][2] = {};
  const unsigned short* wf0 = Wb + (size_t)(32 * w + l15) * 512 + lk8;
  const unsigned short* wf1 = wf0 + (size_t)16 * 512;
  const unsigned short* wg0 = wf0 + (size_t)256 * 512;
  const unsigned short* wg1 = wf0 + (size_t)272 * 512;
  #pragma unroll 4
  for (int kc = 0; kc < 16; ++kc) {
    const int k0 = kc * 32;
    uint4 ubf0 = *(const uint4*)(wf0 + k0);
    uint4 ubf1 = *(const uint4*)(wf1 + k0);
    uint4 ubg0 = *(const uint4*)(wg0 + k0);
    uint4 ubg1 = *(const uint4*)(wg1 + k0);
    const int colb = (k0 + lk8) * 2;
    bf16x8 a[4];
    #pragma unroll
    for (int mf = 0; mf < 4; ++mf)
      a[mf] = *(const bf16x8*)((const char*)As + (mf * 16 + l15) * 1040 + colb);
    bf16x8 vf0 = __builtin_bit_cast(bf16x8, ubf0);
    bf16x8 vf1 = __builtin_bit_cast(bf16x8, ubf1);
    bf16x8 vg0 = __builtin_bit_cast(bf16x8, ubg0);
    bf16x8 vg1 = __builtin_bit_cast(bf16x8, ubg1);
    #pragma unroll
    for (int mf = 0; mf < 4; ++mf) {
      accf[mf][0] = __builtin_amdgcn_mfma_f32_16x16x32_bf16(a[mf], vf0, accf[mf][0], 0, 0, 0);
      accf[mf][1] = __builtin_amdgcn_mfma_f32_16x16x32_bf16(a[mf], vf1, accf[mf][1], 0, 0, 0);
      accg[mf][0] = __builtin_amdgcn_mfma_f32_16x16x32_bf16(a[mf], vg0, accg[mf][0], 0, 0, 0);
      accg[mf][1] = __builtin_amdgcn_mfma_f32_16x16x32_bf16(a[mf], vg1, accg[mf][1], 0, 0, 0);
    }
  }

  // ---- hoist res-GEMM B loads (hide L2 latency under barrier+epilogue)
  const unsigned short* wr0 = Wrb + (size_t)(32 * w + l15) * 256 + lk8;
  const unsigned short* wr1 = wr0 + (size_t)16 * 256;
  uint4 urr[8][2];
  #pragma unroll
  for (int kc = 0; kc < 8; ++kc) {
    urr[kc][0] = *(const uint4*)(wr0 + kc * 32);
    urr[kc][1] = *(const uint4*)(wr1 + kc * 32);
  }
  __syncthreads();   // all As reads done -> safe to overwrite with z

  // ---- gate epilogue: z = tanh(f+bf) * sigmoid(g+bg) -> LDS (aliased)
  unsigned short* Zs = As;
  const int rr0 = (lane >> 4) << 2;            // 0,4,8,12
  const float bfv[2] = { bF[32 * w + l15], bF[32 * w + 16 + l15] };
  const float bgv[2] = { bG[32 * w + l15], bG[32 * w + 16 + l15] };
  #pragma unroll
  for (int mf = 0; mf < 4; ++mf)
    #pragma unroll
    for (int nf = 0; nf < 2; ++nf) {
      int col = 32 * w + nf * 16 + l15;
      #pragma unroll
      for (int j = 0; j < 4; ++j) {
        int row = mf * 16 + rr0 + j;
        float pf = accf[mf][nf][j] + bfv[nf];
        float pg = accg[mf][nf][j] + bgv[nf];
        float e2 = __expf(2.f * pf);
        float th = 1.f - 2.f / (e2 + 1.f);
        float sg = 1.f / (1.f + __expf(-pg));
        *(unsigned short*)((char*)Zs + row * 528 + col * 2) = f2bf(th * sg);
      }
    }
  __syncthreads();

  // ---- res GEMM: per wave 64(M) x 32(N), K=256 from z-LDS
  f32x4 acc[4][2] = {};
  #pragma unroll 4
  for (int kc = 0; kc < 8; ++kc) {
    const int colb = (kc * 32 + lk8) * 2;
    bf16x8 a[4];
    #pragma unroll
    for (int mf = 0; mf < 4; ++mf)
      a[mf] = *(const bf16x8*)((const char*)Zs + (mf * 16 + l15) * 528 + colb);
    bf16x8 v0 = __builtin_bit_cast(bf16x8, urr[kc][0]);
    bf16x8 v1 = __builtin_bit_cast(bf16x8, urr[kc][1]);
    #pragma unroll
    for (int mf = 0; mf < 4; ++mf) {
      acc[mf][0] = __builtin_amdgcn_mfma_f32_16x16x32_bf16(a[mf], v0, acc[mf][0], 0, 0, 0);
      acc[mf][1] = __builtin_amdgcn_mfma_f32_16x16x32_bf16(a[mf], v1, acc[mf][1], 0, 0, 0);
    }
  }

  // ---- residual epilogue: fx = acc + bR; x += fx (fp32 master, in place);
  //      bf16 mirror -> xbb_w (ping-pong); snapshot fx at tt==1023
  const float brv[2] = { bR[32 * w + l15], bR[32 * w + 16 + l15] };
  float* xBf = xb + ((size_t)b << 18);
  unsigned short* xBb = xbb_w + ((size_t)b << 18);
  #pragma unroll
  for (int mf = 0; mf < 4; ++mf)
    #pragma unroll
    for (int j = 0; j < 4; ++j) {
      int tt = tt0 + mf * 16 + rr0 + j;
      if (tt > 1023) continue;
      #pragma unroll
      for (int nf = 0; nf < 2; ++nf) {
        int o = 32 * w + nf * 16 + l15;
        size_t off = ((size_t)tt << 8) + o;
        float fx = acc[mf][nf][j] + brv[nf];
        float xn = xBf[off] + fx;
        xBf[off] = xn;
        xBb[off] = f2bf(xn);
        if (tt == 1023) fxs_i[(size_t)b * 256 + o] = fx;
      }
    }
}

// ---------------- head ----------------
__global__ __launch_bounds__(128) void skip_partial(
    const float* __restrict__ fxs, const float* __restrict__ wskT,
    const float* __restrict__ b_skip, float* __restrict__ part)
{
  int i = blockIdx.x, b = blockIdx.y, s = threadIdx.x;
  __shared__ float fxsh[256];
  fxsh[s]       = fxs[((size_t)i * 16 + b) * 256 + s];
  fxsh[s + 128] = fxs[((size_t)i * 16 + b) * 256 + s + 128];
  __syncthreads();
  float a = b_skip[i * 128 + s];
  const float* wp = wskT + (size_t)i * 256 * 128 + s;
  #pragma unroll 4
  for (int c = 0; c < 256; c++)
    a = fmaf(wp[c * 128], fxsh[c], a);
  part[((size_t)i * 16 + b) * 128 + s] = a;
}

__global__ __launch_bounds__(128) void head2(
    const float* __restrict__ part, const float* __restrict__ w_o1,
    const float* __restrict__ b_o1, const float* __restrict__ w_o2,
    const float* __restrict__ b_o2, const float* __restrict__ w_lin,
    const float* __restrict__ b_lin, const float* __restrict__ Xex,
    float* __restrict__ out)
{
  int b = blockIdx.x, tid = threadIdx.x;
  __shared__ float sk[128];
  __shared__ float h1[64];
  __shared__ float hc[80];
  float a = 0.f;
  for (int i = 0; i < 32; i++) a += part[((size_t)i * 16 + b) * 128 + tid];
  sk[tid] = fmaxf(a, 0.f);
  __syncthreads();
  if (tid < 64) {
    float a1 = b_o1[tid];
    for (int s = 0; s < 128; s++) a1 = fmaf(w_o1[tid * 128 + s], sk[s], a1);
    h1[tid] = fmaxf(a1, 0.f);
  }
  __syncthreads();
  if (tid < 64) {
    float a2 = b_o2[tid];
    for (int j = 0; j < 64; j++) a2 = fmaf(w_o2[tid * 64 + j], h1[j], a2);
    hc[tid] = fmaxf(a2, 0.f);
  }
  if (tid >= 64 && tid < 80) hc[tid] = fmaxf(Xex[b * 16 + (tid - 64)], 0.f);
  __syncthreads();
  if (tid < 24) {
    float a3 = b_lin[tid];
    for (int j = 0; j < 80; j++) a3 = fmaf(w_lin[tid * 80 + j], hc[j], a3);
    out[b * 24 + tid] = a3;
  }
}

extern "C" void kernel_launch(void* const* d_in, const int* in_sizes, int n_in,
                              void* d_out, int out_size, void* d_ws, size_t ws_size,
                              hipStream_t stream)
{
  (void)in_sizes; (void)n_in; (void)out_size; (void)ws_size;
  const float* X     = (const float*)d_in[0];
  const float* Xex   = (const float*)d_in[1];
  const float* w_in  = (const float*)d_in[2];
  const float* b_in  = (const float*)d_in[3];
  const float* w_f   = (const float*)d_in[4];
  const float* b_f   = (const float*)d_in[5];
  const float* w_g   = (const float*)d_in[6];
  const float* b_g   = (const float*)d_in[7];
  const float* w_r   = (const float*)d_in[8];
  const float* b_r   = (const float*)d_in[9];
  const float* w_s   = (const float*)d_in[10];
  const float* b_s   = (const float*)d_in[11];
  const float* w_o1  = (const float*)d_in[12];
  const float* b_o1  = (const float*)d_in[13];
  const float* w_o2  = (const float*)d_in[14];
  const float* b_o2  = (const float*)d_in[15];
  const float* w_lin = (const float*)d_in[16];
  const float* b_lin = (const float*)d_in[17];

  float* ws   = (float*)d_ws;
  float* wskT = ws;                        // 1,048,576 f
  float* xb   = wskT + 1048576;            // 4,194,304 f
  float* fxs  = xb   + 4194304;            // 131,072 f
  float* part = fxs  + 131072;             // 65,536 f
  float* w2   = part + 65536;              // 16,384 f
  unsigned short* Wb   = (unsigned short*)(w2 + 16384);    // 8,388,608 us
  unsigned short* Wrb  = Wb   + 8388608;   // 2,097,152 us
  unsigned short* xbbA = Wrb  + 2097152;   // 4,194,304 us
  unsigned short* xbbB = xbbA + 4194304;   // 4,194,304 us

  transform_fgb <<<16384, 256, 0, stream>>>(w_f, w_g, Wb);
  transform_resb<<<2048,  256, 0, stream>>>(w_r, Wrb);
  transform_skip<<<4096,  256, 0, stream>>>(w_s, wskT);
  transform_w2  <<<64,    256, 0, stream>>>(w_in, w2);
  in_conv<<<1024, 256, 0, stream>>>(X, w2, b_in, xb, xbbA);

  // suffix-window sizes: w[i] = w[i+1] + 2^(i%8), w[32] = 1
  static const int wI[33] = {1021,1020,1018,1014,1006,990,958,894,
                             766,765,763,759,751,735,703,639,
                             511,510,508,504,496,480,448,384,
                             256,255,253,249,241,225,193,129,1};
  for (int i = 0; i < 32; i++) {
    int dd    = 1 << (i & 7);
    int Wout  = wI[i + 1];
    int t_lo  = TBUF - Wout;
    int tiles = (Wout + 63) / 64;
    unsigned short* xin  = (i & 1) ? xbbB : xbbA;
    unsigned short* xout = (i & 1) ? xbbA : xbbB;
    layer_fused<<<tiles * 16, 512, 0, stream>>>(
        xin, xb, xout,
        Wb + (size_t)i * 512 * 512, Wrb + (size_t)i * 256 * 256,
        b_f + i * 256, b_g + i * 256, b_r + i * 256,
        dd, t_lo, fxs + (size_t)i * 16 * 256);
  }
  skip_partial<<<dim3(32, 16), 128, 0, stream>>>(fxs, wskT, b_s, part);
  head2<<<16, 128, 0, stream>>>(part, w_o1, b_o1, w_o2, b_o2, w_lin, b_lin, Xex, (float*)d_out);
}

// Round 9
// 1100.674 us; speedup vs baseline: 1.3298x; 1.2531x over previous
//
#include <hip/hip_runtime.h>
#include <cmath>

#define TBUF 1024
#define RCH  256

typedef __bf16 bf16x8 __attribute__((ext_vector_type(8)));
typedef float  f32x4  __attribute__((ext_vector_type(4)));

__device__ inline unsigned short f2bf(float f) {
  unsigned u = __builtin_bit_cast(unsigned, f);
  u += 0x7FFFu + ((u >> 16) & 1u);
  return (unsigned short)(u >> 16);
}

// ---------------- weight transforms ----------------
// Wb[i][o'][kappa] bf16.  o'<256 -> filter o, o'>=256 -> gate o-256.
// kappa<256 -> current tap (w[...,1]), kappa>=256 -> previous tap (w[...,0]).
__global__ __launch_bounds__(256) void transform_fgb(
    const float* __restrict__ wf, const float* __restrict__ wg, unsigned short* __restrict__ Wb)
{
  int idx = blockIdx.x * 256 + threadIdx.x;      // < 32*512*256
  int c  = idx & 255;
  int op = (idx >> 8) & 511;
  int i  = idx >> 17;
  int o  = op & 255;
  const float* src = (op < 256) ? wf : wg;
  const float2 v = *(const float2*)&src[(((size_t)i * 256 + o) * 256 + c) << 1];
  unsigned short* dst = Wb + ((size_t)i * 512 + op) * 512;
  dst[c]       = f2bf(v.y);   // current tap (k=1)
  dst[256 + c] = f2bf(v.x);   // previous tap (k=0)
}

// Wrb[i][o][c] bf16 (w_res already [o][c])
__global__ __launch_bounds__(256) void transform_resb(
    const float* __restrict__ wr, unsigned short* __restrict__ Wrb)
{
  int idx = blockIdx.x * 256 + threadIdx.x;    // < 32*256*256/4
  float4 v = ((const float4*)wr)[idx];
  uint2 o;
  o.x = (unsigned)f2bf(v.x) | ((unsigned)f2bf(v.y) << 16);
  o.y = (unsigned)f2bf(v.z) | ((unsigned)f2bf(v.w) << 16);
  ((uint2*)Wrb)[idx] = o;
}

// wskT[i][c][s] = w_skip[i][s][c]  (fp32, for head)
__global__ __launch_bounds__(256) void transform_skip(
    const float* __restrict__ wsk, float* __restrict__ wskT)
{
  int idx = blockIdx.x * 256 + threadIdx.x;    // < 32*256*128
  int s = idx & 127;
  int c = (idx >> 7) & 255;
  int i = idx >> 15;
  wskT[idx] = wsk[(i * 128 + s) * 256 + c];
}

// w2[k*32+f][r] = w_in[r][f][k]
__global__ __launch_bounds__(256) void transform_w2(
    const float* __restrict__ w_in, float* __restrict__ w2)
{
  int idx = blockIdx.x * 256 + threadIdx.x;    // < 64*256
  int r = idx & 255;
  int fk = idx >> 8;
  int f = fk & 31, k = fk >> 5;
  w2[idx] = w_in[r * 64 + f * 2 + k];
}

// ---------------- input conv (F=32 -> R=256, K=2, d=1) ----------------
// 1D grid 1024 = 64 chunks x 16 batch, batch FASTEST.
__global__ __launch_bounds__(256) void in_conv(
    const float* __restrict__ X, const float* __restrict__ w2,
    const float* __restrict__ b_in, float* __restrict__ xb,
    unsigned short* __restrict__ xbb)
{
  const int bid   = blockIdx.x;
  const int b     = bid & 15;
  const int chunk = bid >> 4;
  const int r     = threadIdx.x;
  __shared__ float Xs[17][32];
  const int tt0 = chunk << 4;
  const int t0  = tt0 + 1024;
  for (int idx = r; idx < 17 * 32; idx += 256) {
    int row = idx >> 5, f = idx & 31;
    Xs[row][f] = X[((size_t)b * 2048 + (t0 - 1 + row)) * 32 + f];
  }
  __syncthreads();
  float w0[32], w1[32];
  #pragma unroll
  for (int f = 0; f < 32; ++f) {
    w0[f] = w2[f * 256 + r];          // tap k=0 -> x[t-1]
    w1[f] = w2[(32 + f) * 256 + r];   // tap k=1 -> x[t]
  }
  const float bias = b_in[r];
  float4 prev[8], cur[8];
  #pragma unroll
  for (int q = 0; q < 8; ++q) prev[q] = *(const float4*)&Xs[0][q * 4];
  #pragma unroll
  for (int j = 0; j < 16; ++j) {
    #pragma unroll
    for (int q = 0; q < 8; ++q) cur[q] = *(const float4*)&Xs[j + 1][q * 4];
    float a = bias;
    #pragma unroll
    for (int q = 0; q < 8; ++q) {
      a = fmaf(w0[q*4+0], prev[q].x, a); a = fmaf(w1[q*4+0], cur[q].x, a);
      a = fmaf(w0[q*4+1], prev[q].y, a); a = fmaf(w1[q*4+1], cur[q].y, a);
      a = fmaf(w0[q*4+2], prev[q].z, a); a = fmaf(w1[q*4+2], cur[q].z, a);
      a = fmaf(w0[q*4+3], prev[q].w, a); a = fmaf(w1[q*4+3], cur[q].w, a);
    }
    int tt = tt0 + j;
    size_t off = ((size_t)b * TBUF + tt) * RCH + r;
    if (tt < 3) { xb[off] = 0.f; xbb[off] = 0; }
    else        { xb[off] = a;   xbb[off] = f2bf(a); }
    #pragma unroll
    for (int q = 0; q < 8; ++q) prev[q] = cur[q];
  }
}

// ---------------- fused layer: gated dilated conv + res 1x1 + residual ----------------
// r3-best geometry: 512 thr = 8 waves, M=64 rows, full N (512 conv / 256 res).
// A-tile (64 x 512) in LDS, 1040B rows (odd stride = natural bank skew).
// Res-B loads IN-LOOP (hoisting across barrier causes spills - r4/r8 evidence).
// 1D grid tiles*16, batch fastest (XCD pinning). LB(512,4) = r3's proven config.
__global__ __launch_bounds__(512, 4) void layer_fused(
    const unsigned short* __restrict__ xbb_r, float* __restrict__ xb,
    unsigned short* __restrict__ xbb_w,
    const unsigned short* __restrict__ Wb,   // [512][512] bf16
    const unsigned short* __restrict__ Wrb,  // [256][256] bf16
    const float* __restrict__ bF, const float* __restrict__ bG,
    const float* __restrict__ bR,
    int dd, int t_lo, float* __restrict__ fxs_i)
{
  __shared__ __align__(16) unsigned short As[64 * 520];   // 66,560 B; z aliases
  const int bid  = blockIdx.x;
  const int b    = bid & 15;
  const int tile = bid >> 4;
  const int tid  = threadIdx.x;
  const int w    = tid >> 6;
  const int lane = tid & 63;
  const int l15  = lane & 15;
  const int lk8  = (lane >> 4) << 3;          // k-elem offset {0,8,16,24}
  const int tt0  = t_lo + tile * 64;
  const unsigned short* xB = xbb_r + ((size_t)b << 18);

  // ---- stage full A tile: 64 rows x 512 k  (k<256: x[tt], k>=256: x[tt-d])
  #pragma unroll
  for (int it = 0; it < 8; ++it) {
    int flat = it * 512 + tid;
    int r = flat >> 6;                 // 0..63
    int c = flat & 63;                 // 16B slot within row
    int tap = c >> 5;
    int tt = tt0 + r - tap * dd;
    tt = min(max(tt, 0), 1023);
    uint4 v = *(const uint4*)&xB[((size_t)tt << 8) + ((c & 31) << 3)];
    *(uint4*)((char*)As + r * 1040 + (c << 4)) = v;
  }
  __syncthreads();

  // ---- conv GEMM (no barriers): per wave 64(M) x {32 f + 32 g}
  f32x4 accf[4][2] = {};
  f32x4 accg[4][2] = {};
  const unsigned short* wf0 = Wb + (size_t)(32 * w + l15) * 512 + lk8;
  const unsigned short* wf1 = wf0 + (size_t)16 * 512;
  const unsigned short* wg0 = wf0 + (size_t)256 * 512;
  const unsigned short* wg1 = wf0 + (size_t)272 * 512;
  #pragma unroll 4
  for (int kc = 0; kc < 16; ++kc) {
    const int k0 = kc * 32;
    uint4 ubf0 = *(const uint4*)(wf0 + k0);
    uint4 ubf1 = *(const uint4*)(wf1 + k0);
    uint4 ubg0 = *(const uint4*)(wg0 + k0);
    uint4 ubg1 = *(const uint4*)(wg1 + k0);
    const int colb = (k0 + lk8) * 2;
    bf16x8 a[4];
    #pragma unroll
    for (int mf = 0; mf < 4; ++mf)
      a[mf] = *(const bf16x8*)((const char*)As + (mf * 16 + l15) * 1040 + colb);
    bf16x8 vf0 = __builtin_bit_cast(bf16x8, ubf0);
    bf16x8 vf1 = __builtin_bit_cast(bf16x8, ubf1);
    bf16x8 vg0 = __builtin_bit_cast(bf16x8, ubg0);
    bf16x8 vg1 = __builtin_bit_cast(bf16x8, ubg1);
    #pragma unroll
    for (int mf = 0; mf < 4; ++mf) {
      accf[mf][0] = __builtin_amdgcn_mfma_f32_16x16x32_bf16(a[mf], vf0, accf[mf][0], 0, 0, 0);
      accf[mf][1] = __builtin_amdgcn_mfma_f32_16x16x32_bf16(a[mf], vf1, accf[mf][1], 0, 0, 0);
      accg[mf][0] = __builtin_amdgcn_mfma_f32_16x16x32_bf16(a[mf], vg0, accg[mf][0], 0, 0, 0);
      accg[mf][1] = __builtin_amdgcn_mfma_f32_16x16x32_bf16(a[mf], vg1, accg[mf][1], 0, 0, 0);
    }
  }
  __syncthreads();   // all As reads done -> safe to overwrite with z

  // ---- gate epilogue: z = tanh(f+bf) * sigmoid(g+bg) -> LDS (aliased)
  unsigned short* Zs = As;
  const int rr0 = (lane >> 4) << 2;            // 0,4,8,12
  const float bfv[2] = { bF[32 * w + l15], bF[32 * w + 16 + l15] };
  const float bgv[2] = { bG[32 * w + l15], bG[32 * w + 16 + l15] };
  #pragma unroll
  for (int mf = 0; mf < 4; ++mf)
    #pragma unroll
    for (int nf = 0; nf < 2; ++nf) {
      int col = 32 * w + nf * 16 + l15;
      #pragma unroll
      for (int j = 0; j < 4; ++j) {
        int row = mf * 16 + rr0 + j;
        float pf = accf[mf][nf][j] + bfv[nf];
        float pg = accg[mf][nf][j] + bgv[nf];
        float e2 = __expf(2.f * pf);
        float th = 1.f - 2.f / (e2 + 1.f);
        float sg = 1.f / (1.f + __expf(-pg));
        *(unsigned short*)((char*)Zs + row * 528 + col * 2) = f2bf(th * sg);
      }
    }
  __syncthreads();

  // ---- res GEMM: per wave 64(M) x 32(N), K=256 from z-LDS (B loads in-loop)
  f32x4 acc[4][2] = {};
  const unsigned short* wr0 = Wrb + (size_t)(32 * w + l15) * 256 + lk8;
  const unsigned short* wr1 = wr0 + (size_t)16 * 256;
  #pragma unroll 4
  for (int kc = 0; kc < 8; ++kc) {
    uint4 ur0 = *(const uint4*)(wr0 + kc * 32);
    uint4 ur1 = *(const uint4*)(wr1 + kc * 32);
    const int colb = (kc * 32 + lk8) * 2;
    bf16x8 a[4];
    #pragma unroll
    for (int mf = 0; mf < 4; ++mf)
      a[mf] = *(const bf16x8*)((const char*)Zs + (mf * 16 + l15) * 528 + colb);
    bf16x8 v0 = __builtin_bit_cast(bf16x8, ur0);
    bf16x8 v1 = __builtin_bit_cast(bf16x8, ur1);
    #pragma unroll
    for (int mf = 0; mf < 4; ++mf) {
      acc[mf][0] = __builtin_amdgcn_mfma_f32_16x16x32_bf16(a[mf], v0, acc[mf][0], 0, 0, 0);
      acc[mf][1] = __builtin_amdgcn_mfma_f32_16x16x32_bf16(a[mf], v1, acc[mf][1], 0, 0, 0);
    }
  }

  // ---- residual epilogue: fx = acc + bR; x += fx (fp32 master, in place);
  //      bf16 mirror -> xbb_w (ping-pong); snapshot fx at tt==1023
  const float brv[2] = { bR[32 * w + l15], bR[32 * w + 16 + l15] };
  float* xBf = xb + ((size_t)b << 18);
  unsigned short* xBb = xbb_w + ((size_t)b << 18);
  #pragma unroll
  for (int mf = 0; mf < 4; ++mf)
    #pragma unroll
    for (int j = 0; j < 4; ++j) {
      int tt = tt0 + mf * 16 + rr0 + j;
      if (tt > 1023) continue;
      #pragma unroll
      for (int nf = 0; nf < 2; ++nf) {
        int o = 32 * w + nf * 16 + l15;
        size_t off = ((size_t)tt << 8) + o;
        float fx = acc[mf][nf][j] + brv[nf];
        float xn = xBf[off] + fx;
        xBf[off] = xn;
        xBb[off] = f2bf(xn);
        if (tt == 1023) fxs_i[(size_t)b * 256 + o] = fx;
      }
    }
}

// ---------------- head ----------------
__global__ __launch_bounds__(128) void skip_partial(
    const float* __restrict__ fxs, const float* __restrict__ wskT,
    const float* __restrict__ b_skip, float* __restrict__ part)
{
  int i = blockIdx.x, b = blockIdx.y, s = threadIdx.x;
  __shared__ float fxsh[256];
  fxsh[s]       = fxs[((size_t)i * 16 + b) * 256 + s];
  fxsh[s + 128] = fxs[((size_t)i * 16 + b) * 256 + s + 128];
  __syncthreads();
  float a = b_skip[i * 128 + s];
  const float* wp = wskT + (size_t)i * 256 * 128 + s;
  #pragma unroll 4
  for (int c = 0; c < 256; c++)
    a = fmaf(wp[c * 128], fxsh[c], a);
  part[((size_t)i * 16 + b) * 128 + s] = a;
}

__global__ __launch_bounds__(128) void head2(
    const float* __restrict__ part, const float* __restrict__ w_o1,
    const float* __restrict__ b_o1, const float* __restrict__ w_o2,
    const float* __restrict__ b_o2, const float* __restrict__ w_lin,
    const float* __restrict__ b_lin, const float* __restrict__ Xex,
    float* __restrict__ out)
{
  int b = blockIdx.x, tid = threadIdx.x;
  __shared__ float sk[128];
  __shared__ float h1[64];
  __shared__ float hc[80];
  float a = 0.f;
  for (int i = 0; i < 32; i++) a += part[((size_t)i * 16 + b) * 128 + tid];
  sk[tid] = fmaxf(a, 0.f);
  __syncthreads();
  if (tid < 64) {
    float a1 = b_o1[tid];
    for (int s = 0; s < 128; s++) a1 = fmaf(w_o1[tid * 128 + s], sk[s], a1);
    h1[tid] = fmaxf(a1, 0.f);
  }
  __syncthreads();
  if (tid < 64) {
    float a2 = b_o2[tid];
    for (int j = 0; j < 64; j++) a2 = fmaf(w_o2[tid * 64 + j], h1[j], a2);
    hc[tid] = fmaxf(a2, 0.f);
  }
  if (tid >= 64 && tid < 80) hc[tid] = fmaxf(Xex[b * 16 + (tid - 64)], 0.f);
  __syncthreads();
  if (tid < 24) {
    float a3 = b_lin[tid];
    for (int j = 0; j < 80; j++) a3 = fmaf(w_lin[tid * 80 + j], hc[j], a3);
    out[b * 24 + tid] = a3;
  }
}

extern "C" void kernel_launch(void* const* d_in, const int* in_sizes, int n_in,
                              void* d_out, int out_size, void* d_ws, size_t ws_size,
                              hipStream_t stream)
{
  (void)in_sizes; (void)n_in; (void)out_size; (void)ws_size;
  const float* X     = (const float*)d_in[0];
  const float* Xex   = (const float*)d_in[1];
  const float* w_in  = (const float*)d_in[2];
  const float* b_in  = (const float*)d_in[3];
  const float* w_f   = (const float*)d_in[4];
  const float* b_f   = (const float*)d_in[5];
  const float* w_g   = (const float*)d_in[6];
  const float* b_g   = (const float*)d_in[7];
  const float* w_r   = (const float*)d_in[8];
  const float* b_r   = (const float*)d_in[9];
  const float* w_s   = (const float*)d_in[10];
  const float* b_s   = (const float*)d_in[11];
  const float* w_o1  = (const float*)d_in[12];
  const float* b_o1  = (const float*)d_in[13];
  const float* w_o2  = (const float*)d_in[14];
  const float* b_o2  = (const float*)d_in[15];
  const float* w_lin = (const float*)d_in[16];
  const float* b_lin = (const float*)d_in[17];

  float* ws   = (float*)d_ws;
  float* wskT = ws;                        // 1,048,576 f
  float* xb   = wskT + 1048576;            // 4,194,304 f
  float* fxs  = xb   + 4194304;            // 131,072 f
  float* part = fxs  + 131072;             // 65,536 f
  float* w2   = part + 65536;              // 16,384 f
  unsigned short* Wb   = (unsigned short*)(w2 + 16384);    // 8,388,608 us
  unsigned short* Wrb  = Wb   + 8388608;   // 2,097,152 us
  unsigned short* xbbA = Wrb  + 2097152;   // 4,194,304 us
  unsigned short* xbbB = xbbA + 4194304;   // 4,194,304 us

  transform_fgb <<<16384, 256, 0, stream>>>(w_f, w_g, Wb);
  transform_resb<<<2048,  256, 0, stream>>>(w_r, Wrb);
  transform_skip<<<4096,  256, 0, stream>>>(w_s, wskT);
  transform_w2  <<<64,    256, 0, stream>>>(w_in, w2);
  in_conv<<<1024, 256, 0, stream>>>(X, w2, b_in, xb, xbbA);

  // suffix-window sizes: w[i] = w[i+1] + 2^(i%8), w[32] = 1
  static const int wI[33] = {1021,1020,1018,1014,1006,990,958,894,
                             766,765,763,759,751,735,703,639,
                             511,510,508,504,496,480,448,384,
                             256,255,253,249,241,225,193,129,1};
  for (int i = 0; i < 32; i++) {
    int dd    = 1 << (i & 7);
    int Wout  = wI[i + 1];
    int t_lo  = TBUF - Wout;
    int tiles = (Wout + 63) / 64;
    unsigned short* xin  = (i & 1) ? xbbB : xbbA;
    unsigned short* xout = (i & 1) ? xbbA : xbbB;
    layer_fused<<<tiles * 16, 512, 0, stream>>>(
        xin, xb, xout,
        Wb + (size_t)i * 512 * 512, Wrb + (size_t)i * 256 * 256,
        b_f + i * 256, b_g + i * 256, b_r + i * 256,
        dd, t_lo, fxs + (size_t)i * 16 * 256);
  }
  skip_partial<<<dim3(32, 16), 128, 0, stream>>>(fxs, wskT, b_s, part);
  head2<<<16, 128, 0, stream>>>(part, w_o1, b_o1, w_o2, b_o2, w_lin, b_lin, Xex, (float*)d_out);
}